// Round 6
// baseline (59031.140 us; speedup 1.0000x reference)
//
#include <hip/hip_runtime.h>
#include <math.h>

#define HH 1024
#define VV 4096
#define TSTEPS 128
#define NB 256
#define NT 512

// ---------- helpers ----------

__device__ __forceinline__ float sigf(float x) { return 1.0f / (1.0f + expf(-x)); }

// sum across each 16-lane row via DPP; row total lands in lane (row*16+15).
__device__ __forceinline__ float rowsum16(float x) {
  x += __int_as_float(__builtin_amdgcn_update_dpp(0, __float_as_int(x), 0x111, 0xf, 0xf, true));
  x += __int_as_float(__builtin_amdgcn_update_dpp(0, __float_as_int(x), 0x112, 0xf, 0xf, true));
  x += __int_as_float(__builtin_amdgcn_update_dpp(0, __float_as_int(x), 0x114, 0xf, 0xf, true));
  x += __int_as_float(__builtin_amdgcn_update_dpp(0, __float_as_int(x), 0x118, 0xf, 0xf, true));
  return x;
}

// descending top-5 insert, tie -> lower flat index (matches jax.lax.top_k)
__device__ __forceinline__ void ins5(float* bv, int* bi, float v, int i) {
#pragma unroll
  for (int j = 0; j < 5; ++j) {
    if (v > bv[j] || (v == bv[j] && i < bi[j])) {
#pragma unroll
      for (int s = 4; s > j; --s) { bv[s] = bv[s - 1]; bi[s] = bi[s - 1]; }
      bv[j] = v; bi[j] = i;
      break;
    }
  }
}

// NOTE: param must NOT be named 'w' or 'x'/'y'/'z' — member access .w would be
// macro-substituted (R3 compile failure).
#define FMA4(acc, xv, wv) { acc += (xv).x*(wv).x; acc += (xv).y*(wv).y; acc += (xv).z*(wv).z; acc += (xv).w*(wv).w; }

// ---------- setup kernels ----------

// out[C][R] = in[R][C]
__global__ __launch_bounds__(256) void k_transp(const float* __restrict__ in,
                                                float* __restrict__ out, int R, int C) {
  __shared__ float tile[32][33];
  int c0 = blockIdx.x * 32, r0 = blockIdx.y * 32;
  int tx = threadIdx.x & 31, ty = threadIdx.x >> 5;
#pragma unroll
  for (int i = 0; i < 32; i += 8) tile[ty + i][tx] = in[(long)(r0 + ty + i) * C + c0 + tx];
  __syncthreads();
#pragma unroll
  for (int i = 0; i < 32; i += 8) out[(long)(c0 + ty + i) * R + r0 + tx] = tile[tx][ty + i];
}

// C[1024,1024] = A[1024,1024] @ B[1024,1024]   (tn_proj = tn_output @ W_tn)
__global__ __launch_bounds__(256) void k_tnproj(const float* __restrict__ A,
                                                const float* __restrict__ B,
                                                float* __restrict__ C) {
  __shared__ float As[64][20];
  __shared__ float Bs[16][68];
  int tid = threadIdx.x, blk = blockIdx.x;
  int bx = blk & 15, by = blk >> 4;
  int tx = tid & 15, ty = tid >> 4;
  float acc[4][4];
#pragma unroll
  for (int i = 0; i < 4; i++)
#pragma unroll
    for (int j = 0; j < 4; j++) acc[i][j] = 0.f;
  for (int k0 = 0; k0 < 1024; k0 += 16) {
    {
      int row = tid >> 2, q = tid & 3;
      float4 v = *(const float4*)&A[(long)(by * 64 + row) * 1024 + k0 + q * 4];
      As[row][q * 4] = v.x; As[row][q * 4 + 1] = v.y; As[row][q * 4 + 2] = v.z; As[row][q * 4 + 3] = v.w;
    }
    {
      int row = tid >> 4, q = tid & 15;
      float4 v = *(const float4*)&B[(long)(k0 + row) * 1024 + bx * 64 + q * 4];
      *(float4*)&Bs[row][q * 4] = v;
    }
    __syncthreads();
#pragma unroll
    for (int kk = 0; kk < 16; kk++) {
      float a0 = As[ty * 4][kk], a1 = As[ty * 4 + 1][kk], a2 = As[ty * 4 + 2][kk], a3 = As[ty * 4 + 3][kk];
      float4 b4 = *(const float4*)&Bs[kk][tx * 4];
      acc[0][0] += a0 * b4.x; acc[0][1] += a0 * b4.y; acc[0][2] += a0 * b4.z; acc[0][3] += a0 * b4.w;
      acc[1][0] += a1 * b4.x; acc[1][1] += a1 * b4.y; acc[1][2] += a1 * b4.z; acc[1][3] += a1 * b4.w;
      acc[2][0] += a2 * b4.x; acc[2][1] += a2 * b4.y; acc[2][2] += a2 * b4.z; acc[2][3] += a2 * b4.w;
      acc[3][0] += a3 * b4.x; acc[3][1] += a3 * b4.y; acc[3][2] += a3 * b4.z; acc[3][3] += a3 * b4.w;
    }
    __syncthreads();
  }
#pragma unroll
  for (int i = 0; i < 4; i++) {
    float4 v = make_float4(acc[i][0], acc[i][1], acc[i][2], acc[i][3]);
    *(float4*)&C[(long)(by * 64 + ty * 4 + i) * 1024 + bx * 64 + tx * 4] = v;
  }
}

// ---------- persistent megakernel, weights pinned in VGPRs ----------
// 256 blocks x 512 thr. Block owns: G rows = 4 j x 4 gates (j = blk*4..+4),
// J cols = 4 d, L cols = 16 v. Per step: G | sync | J | sync | L(top5/expsum)
// | sync | B(blocks 0-7: beam update) | sync.
//
// CRITICAL (R5 post-mortem): __launch_bounds__(512,2) gives the backend a
// waves/EU RANGE [2,8]; its heuristic picked 4 waves/EU = 128-VGPR budget and
// spilled all 144 weight regs to scratch (90 GB/dispatch traffic, VALUBusy 4.5%).
// amdgpu_waves_per_eu(2,2) pins EXACTLY 2 waves/EU -> 256-VGPR budget.

__global__ __launch_bounds__(NT) __attribute__((amdgpu_waves_per_eu(2, 2))) void k_beam(
    const float* __restrict__ E, const float* __restrict__ Wih,
    const float* __restrict__ Whh, const float* __restrict__ b_lstm,
    const float* __restrict__ tn_proj, const float* __restrict__ WpnT,
    const float* __restrict__ b_joint, const float* __restrict__ WoutT,
    const float* __restrict__ b_out,
    float* __restrict__ h_pre0, float* __restrict__ h_pre1,
    float* __restrict__ c_pre0, float* __restrict__ c_pre1,
    float* __restrict__ h_new0, float* __restrict__ h_new1,
    float* __restrict__ c_new0, float* __restrict__ c_new1,
    float* __restrict__ jbuf, float* __restrict__ expp,
    float* __restrict__ top5v, int* __restrict__ top5i,
    int* __restrict__ preds0, int* __restrict__ preds1,
    float* __restrict__ gscores, int* __restrict__ glens,
    int* __restrict__ gtok, int* __restrict__ gpar, int* __restrict__ gblank,
    unsigned int* bar, float* __restrict__ out) {
  int tid = threadIdx.x, blk = blockIdx.x;
  int wav = tid >> 6, lane = tid & 63;

  __shared__ float xs[5120];     // staging (20 m x 256 k); aliased pv/pi in B
  __shared__ float part[1280];
  __shared__ float lg[640];      // 40 m x 16 v logits (L)
  __shared__ float sls[5];
  __shared__ float outv[5];
  __shared__ int outi[5];
  __shared__ int s_tok[40], s_par[40], s_blank[40];
  __shared__ float bscore[5];
  __shared__ int btok[5], blen[5];
  __shared__ float nsc[5];
  __shared__ int ntk[5], nln[5], nkp[5], nbl[5], nol[5];
  __shared__ int s_best[8];
  __shared__ float s_maxn[8];
  float* pv = xs;                 // 512*5 floats
  int* pi = (int*)&xs[2560];      // 512*5 ints

  // ---- load pinned weights (once) ----
  float4 wG[2][8];                // G: rows 2w,2w+1 of 16 (row16 = jl*4+g)
#pragma unroll
  for (int rr = 0; rr < 2; rr++) {
    int row16 = wav * 2 + rr;
    int jl = row16 >> 2, g = row16 & 3;
    long grow = (long)(g * HH + blk * 4 + jl) * HH;
#pragma unroll
    for (int q = 0; q < 4; q++) wG[rr][q] = *(const float4*)&Wih[grow + q * 256 + lane * 4];
#pragma unroll
    for (int q = 4; q < 8; q++) wG[rr][q] = *(const float4*)&Whh[grow + (q - 4) * 256 + lane * 4];
  }
  float4 wJ[4];                   // J: col d = blk*4 + (wav&3)
  {
    long drow = (long)(blk * 4 + (wav & 3)) * HH;
#pragma unroll
    for (int q = 0; q < 4; q++) wJ[q] = *(const float4*)&WpnT[drow + q * 256 + lane * 4];
  }
  float4 wL[4][4];                // L: cols v = blk*16 + (wav&3)*4 + r
#pragma unroll
  for (int r = 0; r < 4; r++) {
    long vrow = (long)(blk * 16 + (wav & 3) * 4 + r) * HH;
#pragma unroll
    for (int q = 0; q < 4; q++) wL[r][q] = *(const float4*)&WoutT[vrow + q * 256 + lane * 4];
  }

  // ---- init beam state (blocks 0-7 own batch blk) ----
  if (blk < 8) {
    if (tid < 5) { bscore[tid] = (tid == 0) ? 0.f : -1e9f; btok[tid] = 0; blen[tid] = 0; }
    for (int i = tid; i < 640; i += NT) preds0[blk * 640 + i] = 0;
  }
  __syncthreads();

  unsigned int target = 0;
  auto gsync = [&]() {
    __syncthreads();
    if (tid == 0) {
      target += NB;
      __threadfence();
      __hip_atomic_fetch_add(bar, 1u, __ATOMIC_RELAXED, __HIP_MEMORY_SCOPE_AGENT);
      while (__hip_atomic_load(bar, __ATOMIC_RELAXED, __HIP_MEMORY_SCOPE_AGENT) < target)
        __builtin_amdgcn_s_sleep(1);
      __threadfence();
    }
    __syncthreads();
  };

  for (int t = 0; t < TSTEPS; ++t) {
    const float* h_pre_in = (t & 1) ? h_pre1 : h_pre0;
    const float* h_new_in = (t & 1) ? h_new1 : h_new0;
    const float* c_pre_in = (t & 1) ? c_pre1 : c_pre0;
    const float* c_new_in = (t & 1) ? c_new1 : c_new0;
    float* h_pre_o = (t & 1) ? h_pre0 : h_pre1;
    float* h_new_o = (t & 1) ? h_new0 : h_new1;
    float* c_pre_o = (t & 1) ? c_pre0 : c_pre1;
    float* c_new_o = (t & 1) ? c_new0 : c_new1;

    // ---- phase G: gather + gates GEMM + cell ----
    {
      if (tid < 40) {
        if (t == 0) { s_tok[tid] = 0; s_par[tid] = tid; s_blank[tid] = 1; }
        else { s_tok[tid] = gtok[tid]; s_par[tid] = gpar[tid]; s_blank[tid] = gblank[tid]; }
      }
      __syncthreads();
      for (int half = 0; half < 2; ++half) {
        float accg[2][20];
#pragma unroll
        for (int rr = 0; rr < 2; rr++)
#pragma unroll
          for (int mm = 0; mm < 20; mm++) accg[rr][mm] = 0.f;
#pragma unroll
        for (int q = 0; q < 8; ++q) {          // MUST unroll: wG[.][q]
          for (int f = tid; f < 1280; f += NT) {
            int s = f >> 6, l4 = (f & 63) * 4;
            int m = half * 20 + s;
            float4 v;
            if (q < 4) v = *(const float4*)&E[(long)s_tok[m] * HH + q * 256 + l4];
            else if (t == 0) v = make_float4(0.f, 0.f, 0.f, 0.f);
            else {
              const float* hb = s_blank[m] ? h_pre_in : h_new_in;
              v = *(const float4*)&hb[(long)s_par[m] * HH + (q - 4) * 256 + l4];
            }
            *(float4*)&xs[f * 4] = v;
            if (q >= 4 && blk == 0) *(float4*)&h_pre_o[(long)m * HH + (q - 4) * 256 + l4] = v;
          }
          __syncthreads();
#pragma unroll
          for (int mm = 0; mm < 20; ++mm) {
            float4 x = *(const float4*)&xs[mm * 256 + lane * 4];
            FMA4(accg[0][mm], x, wG[0][q]);
            FMA4(accg[1][mm], x, wG[1][q]);
          }
          __syncthreads();
        }
#pragma unroll
        for (int rr = 0; rr < 2; rr++)
#pragma unroll
          for (int mm = 0; mm < 20; mm++) accg[rr][mm] = rowsum16(accg[rr][mm]);
        if ((lane & 15) == 15) {
          int grp = lane >> 4;
#pragma unroll
          for (int rr = 0; rr < 2; rr++)
#pragma unroll
            for (int mm = 0; mm < 20; mm++)
              part[(wav * 4 + grp) * 40 + rr * 20 + mm] = accg[rr][mm];
        }
        __syncthreads();
        if (tid < 80) {                         // cell: 20 m x 4 j_local
          int mm = tid >> 2, jl = tid & 3;
          int m = half * 20 + mm;
          int j = blk * 4 + jl;
          float gate[4];
#pragma unroll
          for (int g = 0; g < 4; g++) {
            int row16 = jl * 4 + g, w_ = row16 >> 1, rr = row16 & 1;
            float s = 0.f;
#pragma unroll
            for (int grp = 0; grp < 4; grp++) s += part[(w_ * 4 + grp) * 40 + rr * 20 + mm];
            gate[g] = s + b_lstm[g * HH + j];
          }
          float csel;
          if (t == 0) csel = 0.f;
          else {
            const float* cb = s_blank[m] ? c_pre_in : c_new_in;
            csel = cb[(long)s_par[m] * HH + j];
          }
          float cn = sigf(gate[1]) * csel + sigf(gate[0]) * tanhf(gate[2]);
          float hn = sigf(gate[3]) * tanhf(cn);
          long o = (long)m * HH + j;
          h_new_o[o] = hn; c_new_o[o] = cn; c_pre_o[o] = csel;
        }
        __syncthreads();
      }
    }
    gsync();

    // ---- phase J: joint = tanh(tn + h_new @ W_pn + b_joint) ----
    {
      int mh = wav >> 2;
      for (int p = 0; p < 2; ++p) {
        float accj[10];
#pragma unroll
        for (int i = 0; i < 10; i++) accj[i] = 0.f;
#pragma unroll
        for (int q = 0; q < 4; ++q) {          // MUST unroll: wJ[q]
          for (int f = tid; f < 1280; f += NT) {
            int s = f >> 6, l4 = (f & 63) * 4;
            int m = (s >= 10) ? (20 + p * 10 + s - 10) : (p * 10 + s);
            *(float4*)&xs[f * 4] = *(const float4*)&h_new_o[(long)m * HH + q * 256 + l4];
          }
          __syncthreads();
#pragma unroll
          for (int i = 0; i < 10; ++i) {
            float4 x = *(const float4*)&xs[(mh * 10 + i) * 256 + lane * 4];
            FMA4(accj[i], x, wJ[q]);
          }
          __syncthreads();
        }
#pragma unroll
        for (int i = 0; i < 10; i++) accj[i] = rowsum16(accj[i]);
        if ((lane & 15) == 15) {
          int grp = lane >> 4;
#pragma unroll
          for (int i = 0; i < 10; i++) part[(wav * 4 + grp) * 10 + i] = accj[i];
        }
        __syncthreads();
        if (tid < 80) {
          int m_i = tid >> 2, dl2 = tid & 3;
          int mh2 = (m_i >= 10) ? 1 : 0, i = m_i - mh2 * 10;
          int m = mh2 * 20 + p * 10 + i;
          int w2 = mh2 * 4 + dl2;
          float s = 0.f;
#pragma unroll
          for (int grp = 0; grp < 4; grp++) s += part[(w2 * 4 + grp) * 10 + i];
          int d2 = blk * 4 + dl2, b = m / 5;
          float val = s + tn_proj[((long)b * TSTEPS + t) * HH + d2] + b_joint[d2];
          jbuf[(long)m * HH + d2] = tanhf(val);
        }
        __syncthreads();
      }
    }
    gsync();

    // ---- phase L: logits slice (16 v) + local top5 + expsum partial ----
    {
      int mh = wav >> 2;
      for (int p = 0; p < 2; ++p) {
        float accl[4][10];
#pragma unroll
        for (int r = 0; r < 4; r++)
#pragma unroll
          for (int i = 0; i < 10; i++) accl[r][i] = 0.f;
#pragma unroll
        for (int q = 0; q < 4; ++q) {          // MUST unroll: wL[.][q]
          for (int f = tid; f < 1280; f += NT) {
            int s = f >> 6, l4 = (f & 63) * 4;
            int m = (s >= 10) ? (20 + p * 10 + s - 10) : (p * 10 + s);
            *(float4*)&xs[f * 4] = *(const float4*)&jbuf[(long)m * HH + q * 256 + l4];
          }
          __syncthreads();
#pragma unroll
          for (int i = 0; i < 10; ++i) {
            float4 x = *(const float4*)&xs[(mh * 10 + i) * 256 + lane * 4];
#pragma unroll
            for (int r = 0; r < 4; r++) FMA4(accl[r][i], x, wL[r][q]);
          }
          __syncthreads();
        }
#pragma unroll
        for (int r = 0; r < 4; r++)
#pragma unroll
          for (int i = 0; i < 10; i++) accl[r][i] = rowsum16(accl[r][i]);
        if ((lane & 15) == 15) {
          int grp = lane >> 4;
#pragma unroll
          for (int r = 0; r < 4; r++)
#pragma unroll
            for (int i = 0; i < 10; i++)
              part[(wav * 4 + grp) * 40 + r * 10 + i] = accl[r][i];
        }
        __syncthreads();
        if (tid < 320) {
          int m_i = tid >> 4, vloc = tid & 15;
          int mh2 = (m_i >= 10) ? 1 : 0, i = m_i - mh2 * 10;
          int m = mh2 * 20 + p * 10 + i;
          int vh2 = vloc >> 2, r = vloc & 3;
          int w2 = mh2 * 4 + vh2;
          float s = 0.f;
#pragma unroll
          for (int grp = 0; grp < 4; grp++) s += part[(w2 * 4 + grp) * 40 + r * 10 + i];
          lg[m * 16 + vloc] = s + b_out[blk * 16 + vloc];
        }
        __syncthreads();
      }
      if (tid < 40) {
        float bv[5]; int bi[5];
#pragma unroll
        for (int j = 0; j < 5; j++) { bv[j] = -3.0e38f; bi[j] = 0x7fffffff; }
        float es = 0.f;
        int cbase = (tid % 5) * 4096 + blk * 16;
#pragma unroll
        for (int vloc = 0; vloc < 16; vloc++) {
          float v = lg[tid * 16 + vloc];
          es += expf(v);
          ins5(bv, bi, v, cbase + vloc);
        }
        int toff = (tid * 256 + blk) * 5;
#pragma unroll
        for (int r = 0; r < 5; r++) { top5v[toff + r] = bv[r]; top5i[toff + r] = bi[r]; }
        expp[tid * 256 + blk] = es;
      }
    }
    gsync();

    // ---- phase B: beam update (blocks 0-7; block = batch) ----
    if (blk < 8) {
      int b = blk;
      int u = t + 1;
      if (wav < 5) {                       // expsum reduce per hyp
        int m = b * 5 + wav;
        float s = expp[m * 256 + lane] + expp[m * 256 + 64 + lane]
                + expp[m * 256 + 128 + lane] + expp[m * 256 + 192 + lane];
#pragma unroll
        for (int off2 = 32; off2 >= 1; off2 >>= 1) s += __shfl_xor(s, off2, 64);
        if (lane == 0) sls[wav] = bscore[wav] - logf(s);
      }
      __syncthreads();
      float bv[5]; int bi[5];
#pragma unroll
      for (int j = 0; j < 5; j++) { bv[j] = -3.0e38f; bi[j] = 0x7fffffff; }
      for (int e = tid; e < 6400; e += NT) {
        int hyp = e / 1280, rem = e - hyp * 1280;
        int blk_i = rem / 5, r = rem - blk_i * 5;
        int idx = ((b * 5 + hyp) * 256 + blk_i) * 5 + r;
        ins5(bv, bi, top5v[idx] + sls[hyp], top5i[idx]);
      }
      __syncthreads();                     // xs free (pv/pi alias)
#pragma unroll
      for (int j = 0; j < 5; j++) { pv[tid * 5 + j] = bv[j]; pi[tid * 5 + j] = bi[j]; }
      __syncthreads();
      if (tid < 64) {
        for (int srcT = tid + 64; srcT < NT; srcT += 64)
#pragma unroll
          for (int j = 0; j < 5; j++) ins5(bv, bi, pv[srcT * 5 + j], pi[srcT * 5 + j]);
        for (int r = 0; r < 5; r++) {
          float mv = bv[0]; int mi = bi[0];
#pragma unroll
          for (int off2 = 32; off2 >= 1; off2 >>= 1) {
            float ov = __shfl_xor(mv, off2, 64);
            int oi = __shfl_xor(mi, off2, 64);
            if (ov > mv || (ov == mv && oi < mi)) { mv = ov; mi = oi; }
          }
          if (bv[0] == mv && bi[0] == mi) {
            bv[0] = bv[1]; bi[0] = bi[1]; bv[1] = bv[2]; bi[1] = bi[2];
            bv[2] = bv[3]; bi[2] = bi[3]; bv[3] = bv[4]; bi[3] = bi[4];
            bv[4] = -3.0e38f; bi[4] = 0x7fffffff;
          }
          if (tid == 0) { outv[r] = mv; outi[r] = mi; }
        }
      }
      __syncthreads();
      if (tid == 0) {
#pragma unroll
        for (int j = 0; j < 5; j++) {
          int idx = outi[j], kp = idx >> 12, tok = idx & 4095;
          int isb = (tok == 0) ? 1 : 0;
          nsc[j] = outv[j];
          nkp[j] = kp;
          nbl[j] = isb;
          ntk[j] = isb ? btok[kp] : tok;
          nol[j] = blen[kp];
          nln[j] = blen[kp] + (isb ? 0 : 1);
        }
#pragma unroll
        for (int j = 0; j < 5; j++) {
          bscore[j] = nsc[j]; btok[j] = ntk[j]; blen[j] = nln[j];
          int gm = b * 5 + j;
          gscores[gm] = nsc[j]; glens[gm] = nln[j];
          gtok[gm] = ntk[j]; gpar[gm] = b * 5 + nkp[j]; gblank[gm] = nbl[j];
        }
      }
      __syncthreads();
      {
        const int* pip = ((u - 1) & 1) ? preds1 : preds0;
        int* pop = (u & 1) ? preds1 : preds0;
        for (int cell = tid; cell < 640; cell += NT) {
          int j = cell >> 7, pos = cell & 127;
          int v = pip[(b * 5 + nkp[j]) * 128 + pos];
          if (!nbl[j] && pos == nol[j]) v = ntk[j];
          pop[(b * 5 + j) * 128 + pos] = v;
        }
      }
    }
    gsync();
  }

  // ---- final output (block 0) ----
  if (blk == 0) {
    if (tid < 40) out[1033 + tid] = gscores[tid] / (float)(glens[tid] + 1);
    if (tid < 8) {
      float bvn = -3.0e38f; int bk = 0;
      for (int k = 0; k < 5; k++) {
        float n = gscores[tid * 5 + k] / (float)(glens[tid * 5 + k] + 1);
        if (n > bvn) { bvn = n; bk = k; }
      }
      s_best[tid] = bk; s_maxn[tid] = bvn;
      out[1024 + tid] = (float)glens[tid * 5 + bk];
    }
    __syncthreads();
    if (tid == 0) {
      float s = 0;
      for (int b = 0; b < 8; b++) s += expf(s_maxn[b]);
      out[1032] = s / 8.f;
    }
    for (int cI = tid; cI < 1024; cI += NT) {
      int b = cI >> 7, pos = cI & 127;
      out[cI] = (float)preds0[(b * 5 + s_best[b]) * 128 + pos];  // u=128 -> preds0
    }
  }
}

// ---------- launch ----------

extern "C" void kernel_launch(void* const* d_in, const int* in_sizes, int n_in,
                              void* d_out, int out_size, void* d_ws, size_t ws_size,
                              hipStream_t stream) {
  const float* tn   = (const float*)d_in[0];
  const float* E    = (const float*)d_in[1];
  const float* Wih  = (const float*)d_in[2];
  const float* Whh  = (const float*)d_in[3];
  const float* bl   = (const float*)d_in[4];
  const float* Wtn  = (const float*)d_in[5];
  const float* Wpn  = (const float*)d_in[6];
  const float* bj   = (const float*)d_in[7];
  const float* Wout = (const float*)d_in[8];
  const float* bo   = (const float*)d_in[9];
  float* out = (float*)d_out;

  unsigned int* bar = (unsigned int*)d_ws;       // 256 B reserved
  float* w = (float*)d_ws + 64;
  size_t off = 0;
  float* tn_proj = w + off; off += 1048576;
  float* WpnT    = w + off; off += 1048576;
  float* WoutT   = w + off; off += 4194304;
  float* jbuf    = w + off; off += 40960;
  float* expp    = w + off; off += 10240;        // [40][256]
  float* top5v   = w + off; off += 51200;        // [40][256][5]
  float* h_pre0  = w + off; off += 40960;
  float* h_pre1  = w + off; off += 40960;
  float* c_pre0  = w + off; off += 40960;
  float* c_pre1  = w + off; off += 40960;
  float* h_new0  = w + off; off += 40960;
  float* h_new1  = w + off; off += 40960;
  float* c_new0  = w + off; off += 40960;
  float* c_new1  = w + off; off += 40960;
  float* gscores = w + off; off += 40;
  int* ib = (int*)(w + off);
  int* top5i  = ib; ib += 51200;
  int* preds0 = ib; ib += 5120;
  int* preds1 = ib; ib += 5120;
  int* glens  = ib; ib += 40;
  int* gtok   = ib; ib += 40;
  int* gpar   = ib; ib += 40;
  int* gblank = ib; ib += 40;
  if (ws_size < (size_t)(64 + off + 61600) * 4) return;   // ~27.2 MB

  (void)hipMemsetAsync(bar, 0, 256, stream);
  k_transp<<<dim3(32, 32), 256, 0, stream>>>(Wpn, WpnT, 1024, 1024);
  k_transp<<<dim3(128, 32), 256, 0, stream>>>(Wout, WoutT, 1024, 4096);
  k_tnproj<<<256, 256, 0, stream>>>(tn, Wtn, tn_proj);

  void* args[] = { (void*)&E, (void*)&Wih, (void*)&Whh, (void*)&bl,
                   (void*)&tn_proj, (void*)&WpnT, (void*)&bj, (void*)&WoutT, (void*)&bo,
                   (void*)&h_pre0, (void*)&h_pre1, (void*)&c_pre0, (void*)&c_pre1,
                   (void*)&h_new0, (void*)&h_new1, (void*)&c_new0, (void*)&c_new1,
                   (void*)&jbuf, (void*)&expp, (void*)&top5v, (void*)&top5i,
                   (void*)&preds0, (void*)&preds1, (void*)&gscores, (void*)&glens,
                   (void*)&gtok, (void*)&gpar, (void*)&gblank,
                   (void*)&bar, (void*)&out };
  (void)hipLaunchCooperativeKernel((void*)k_beam, dim3(NB), dim3(NT), args, 0, stream);
}

// Round 7
// 53755.780 us; speedup vs baseline: 1.0981x; 1.0981x over previous
//
#include <hip/hip_runtime.h>
#include <math.h>

#define HH 1024
#define VV 4096
#define TSTEPS 128
#define NB 256
#define NT 512

// ---------- helpers ----------

__device__ __forceinline__ float sigf(float x) { return 1.0f / (1.0f + expf(-x)); }

// sum across each 16-lane row via DPP; row total lands in lane (row*16+15).
__device__ __forceinline__ float rowsum16(float x) {
  x += __int_as_float(__builtin_amdgcn_update_dpp(0, __float_as_int(x), 0x111, 0xf, 0xf, true));
  x += __int_as_float(__builtin_amdgcn_update_dpp(0, __float_as_int(x), 0x112, 0xf, 0xf, true));
  x += __int_as_float(__builtin_amdgcn_update_dpp(0, __float_as_int(x), 0x114, 0xf, 0xf, true));
  x += __int_as_float(__builtin_amdgcn_update_dpp(0, __float_as_int(x), 0x118, 0xf, 0xf, true));
  return x;
}

// descending top-5 insert, tie -> lower flat index (matches jax.lax.top_k)
__device__ __forceinline__ void ins5(float* bv, int* bi, float v, int i) {
#pragma unroll
  for (int j = 0; j < 5; ++j) {
    if (v > bv[j] || (v == bv[j] && i < bi[j])) {
#pragma unroll
      for (int s = 4; s > j; --s) { bv[s] = bv[s - 1]; bi[s] = bi[s - 1]; }
      bv[j] = v; bi[j] = i;
      break;
    }
  }
}

// NOTE: param must NOT be named 'w' or 'x'/'y'/'z' — member access .w would be
// macro-substituted (R3 compile failure).
#define FMA4(acc, xv, wv) { acc += (xv).x*(wv).x; acc += (xv).y*(wv).y; acc += (xv).z*(wv).z; acc += (xv).w*(wv).w; }

// ---------- setup kernels ----------

// out[C][R] = in[R][C]
__global__ __launch_bounds__(256) void k_transp(const float* __restrict__ in,
                                                float* __restrict__ out, int R, int C) {
  __shared__ float tile[32][33];
  int c0 = blockIdx.x * 32, r0 = blockIdx.y * 32;
  int tx = threadIdx.x & 31, ty = threadIdx.x >> 5;
#pragma unroll
  for (int i = 0; i < 32; i += 8) tile[ty + i][tx] = in[(long)(r0 + ty + i) * C + c0 + tx];
  __syncthreads();
#pragma unroll
  for (int i = 0; i < 32; i += 8) out[(long)(c0 + ty + i) * R + r0 + tx] = tile[tx][ty + i];
}

// C[1024,1024] = A[1024,1024] @ B[1024,1024]   (tn_proj = tn_output @ W_tn)
__global__ __launch_bounds__(256) void k_tnproj(const float* __restrict__ A,
                                                const float* __restrict__ B,
                                                float* __restrict__ C) {
  __shared__ float As[64][20];
  __shared__ float Bs[16][68];
  int tid = threadIdx.x, blk = blockIdx.x;
  int bx = blk & 15, by = blk >> 4;
  int tx = tid & 15, ty = tid >> 4;
  float acc[4][4];
#pragma unroll
  for (int i = 0; i < 4; i++)
#pragma unroll
    for (int j = 0; j < 4; j++) acc[i][j] = 0.f;
  for (int k0 = 0; k0 < 1024; k0 += 16) {
    {
      int row = tid >> 2, q = tid & 3;
      float4 v = *(const float4*)&A[(long)(by * 64 + row) * 1024 + k0 + q * 4];
      As[row][q * 4] = v.x; As[row][q * 4 + 1] = v.y; As[row][q * 4 + 2] = v.z; As[row][q * 4 + 3] = v.w;
    }
    {
      int row = tid >> 4, q = tid & 15;
      float4 v = *(const float4*)&B[(long)(k0 + row) * 1024 + bx * 64 + q * 4];
      *(float4*)&Bs[row][q * 4] = v;
    }
    __syncthreads();
#pragma unroll
    for (int kk = 0; kk < 16; kk++) {
      float a0 = As[ty * 4][kk], a1 = As[ty * 4 + 1][kk], a2 = As[ty * 4 + 2][kk], a3 = As[ty * 4 + 3][kk];
      float4 b4 = *(const float4*)&Bs[kk][tx * 4];
      acc[0][0] += a0 * b4.x; acc[0][1] += a0 * b4.y; acc[0][2] += a0 * b4.z; acc[0][3] += a0 * b4.w;
      acc[1][0] += a1 * b4.x; acc[1][1] += a1 * b4.y; acc[1][2] += a1 * b4.z; acc[1][3] += a1 * b4.w;
      acc[2][0] += a2 * b4.x; acc[2][1] += a2 * b4.y; acc[2][2] += a2 * b4.z; acc[2][3] += a2 * b4.w;
      acc[3][0] += a3 * b4.x; acc[3][1] += a3 * b4.y; acc[3][2] += a3 * b4.z; acc[3][3] += a3 * b4.w;
    }
    __syncthreads();
  }
#pragma unroll
  for (int i = 0; i < 4; i++) {
    float4 v = make_float4(acc[i][0], acc[i][1], acc[i][2], acc[i][3]);
    *(float4*)&C[(long)(by * 64 + ty * 4 + i) * 1024 + bx * 64 + tx * 4] = v;
  }
}

// ---------- persistent megakernel ----------
// 256 blocks x 512 thr, 1 block/CU (LDS-forced). Weight residency (R6 lesson —
// registers can't hold 208 KB/block under the RA's 128-reg budget):
//   wG (16 gate-rows x 2048 = 128 KB)  -> LDS, loaded once.
//   wJ (4 d-rows    x 1024 = 16 KB)   -> 16 persistent VGPRs.
//   wL (16 v-rows   x 1024 = 64 KB)   -> streamed from L2/LLC per (p,q), 16 live regs.
// Per step: G | sync | J | sync | L(top5/expsum) | sync | B(blocks 0-7) | sync.

__global__ __launch_bounds__(NT, 2) void k_beam(
    const float* __restrict__ E, const float* __restrict__ Wih,
    const float* __restrict__ Whh, const float* __restrict__ b_lstm,
    const float* __restrict__ tn_proj, const float* __restrict__ WpnT,
    const float* __restrict__ b_joint, const float* __restrict__ WoutT,
    const float* __restrict__ b_out,
    float* __restrict__ h_pre0, float* __restrict__ h_pre1,
    float* __restrict__ c_pre0, float* __restrict__ c_pre1,
    float* __restrict__ h_new0, float* __restrict__ h_new1,
    float* __restrict__ c_new0, float* __restrict__ c_new1,
    float* __restrict__ jbuf, float* __restrict__ expp,
    float* __restrict__ top5v, int* __restrict__ top5i,
    int* __restrict__ preds0, int* __restrict__ preds1,
    float* __restrict__ gscores, int* __restrict__ glens,
    int* __restrict__ gtok, int* __restrict__ gpar, int* __restrict__ gblank,
    unsigned int* bar, float* __restrict__ out) {
  int tid = threadIdx.x, blk = blockIdx.x;
  int wav = tid >> 6, lane = tid & 63;

  __shared__ float wGs[32768];   // 16 rows x 2048 (Wih||Whh), 128 KB, resident
  __shared__ float xs[5120];     // staging (20 m x 256 k); aliased pv/pi in B
  __shared__ float part[1280];
  __shared__ float lg[640];      // 40 m x 16 v logits (L)
  __shared__ float sls[5];
  __shared__ float outv[5];
  __shared__ int outi[5];
  __shared__ int s_tok[40], s_par[40], s_blank[40];
  __shared__ float bscore[5];
  __shared__ int btok[5], blen[5];
  __shared__ float nsc[5];
  __shared__ int ntk[5], nln[5], nkp[5], nbl[5], nol[5];
  __shared__ int s_best[8];
  __shared__ float s_maxn[8];
  float* pv = xs;                 // 512*5 floats
  int* pi = (int*)&xs[2560];      // 512*5 ints

  // ---- load wG into LDS (once): row16 = jl*4+g -> W*[g*HH + blk*4 + jl] ----
  for (int i = tid; i < 8192; i += NT) {       // 8192 float4
    int row16 = i >> 9;                        // 512 float4 per 2048-float row
    int k4 = (i & 511) * 4;
    int jl = row16 >> 2, g = row16 & 3;
    long grow = (long)(g * HH + blk * 4 + jl) * HH;
    float4 v = (k4 < 1024) ? *(const float4*)&Wih[grow + k4]
                           : *(const float4*)&Whh[grow + k4 - 1024];
    *(float4*)&wGs[row16 * 2048 + k4] = v;
  }

  // ---- wJ persistent (16 VGPRs): col d = blk*4 + (wav&3) ----
  float4 wJ[4];
  {
    long drow = (long)(blk * 4 + (wav & 3)) * HH;
#pragma unroll
    for (int q = 0; q < 4; q++) wJ[q] = *(const float4*)&WpnT[drow + q * 256 + lane * 4];
  }

  // ---- init beam state (blocks 0-7 own batch blk) ----
  if (blk < 8) {
    if (tid < 5) { bscore[tid] = (tid == 0) ? 0.f : -1e9f; btok[tid] = 0; blen[tid] = 0; }
    for (int i = tid; i < 640; i += NT) preds0[blk * 640 + i] = 0;
  }
  __syncthreads();

  unsigned int target = 0;
  auto gsync = [&]() {
    __syncthreads();
    if (tid == 0) {
      target += NB;
      __threadfence();
      __hip_atomic_fetch_add(bar, 1u, __ATOMIC_RELAXED, __HIP_MEMORY_SCOPE_AGENT);
      while (__hip_atomic_load(bar, __ATOMIC_RELAXED, __HIP_MEMORY_SCOPE_AGENT) < target)
        __builtin_amdgcn_s_sleep(1);
      __threadfence();
    }
    __syncthreads();
  };

  for (int t = 0; t < TSTEPS; ++t) {
    const float* h_pre_in = (t & 1) ? h_pre1 : h_pre0;
    const float* h_new_in = (t & 1) ? h_new1 : h_new0;
    const float* c_pre_in = (t & 1) ? c_pre1 : c_pre0;
    const float* c_new_in = (t & 1) ? c_new1 : c_new0;
    float* h_pre_o = (t & 1) ? h_pre0 : h_pre1;
    float* h_new_o = (t & 1) ? h_new0 : h_new1;
    float* c_pre_o = (t & 1) ? c_pre0 : c_pre1;
    float* c_new_o = (t & 1) ? c_new0 : c_new1;

    // ---- phase G: gather + gates GEMM + cell (weights from LDS) ----
    {
      if (tid < 40) {
        if (t == 0) { s_tok[tid] = 0; s_par[tid] = tid; s_blank[tid] = 1; }
        else { s_tok[tid] = gtok[tid]; s_par[tid] = gpar[tid]; s_blank[tid] = gblank[tid]; }
      }
      __syncthreads();
      for (int half = 0; half < 2; ++half) {
        float accg[2][20];
#pragma unroll
        for (int rr = 0; rr < 2; rr++)
#pragma unroll
          for (int mm = 0; mm < 20; mm++) accg[rr][mm] = 0.f;
#pragma unroll
        for (int q = 0; q < 8; ++q) {
          for (int f = tid; f < 1280; f += NT) {
            int s = f >> 6, l4 = (f & 63) * 4;
            int m = half * 20 + s;
            float4 v;
            if (q < 4) v = *(const float4*)&E[(long)s_tok[m] * HH + q * 256 + l4];
            else if (t == 0) v = make_float4(0.f, 0.f, 0.f, 0.f);
            else {
              const float* hb = s_blank[m] ? h_pre_in : h_new_in;
              v = *(const float4*)&hb[(long)s_par[m] * HH + (q - 4) * 256 + l4];
            }
            *(float4*)&xs[f * 4] = v;
            if (q >= 4 && blk == 0) *(float4*)&h_pre_o[(long)m * HH + (q - 4) * 256 + l4] = v;
          }
          __syncthreads();
          float4 w0 = *(const float4*)&wGs[(wav * 2 + 0) * 2048 + q * 256 + lane * 4];
          float4 w1 = *(const float4*)&wGs[(wav * 2 + 1) * 2048 + q * 256 + lane * 4];
#pragma unroll
          for (int mm = 0; mm < 20; ++mm) {
            float4 x = *(const float4*)&xs[mm * 256 + lane * 4];
            FMA4(accg[0][mm], x, w0);
            FMA4(accg[1][mm], x, w1);
          }
          __syncthreads();
        }
#pragma unroll
        for (int rr = 0; rr < 2; rr++)
#pragma unroll
          for (int mm = 0; mm < 20; mm++) accg[rr][mm] = rowsum16(accg[rr][mm]);
        if ((lane & 15) == 15) {
          int grp = lane >> 4;
#pragma unroll
          for (int rr = 0; rr < 2; rr++)
#pragma unroll
            for (int mm = 0; mm < 20; mm++)
              part[(wav * 4 + grp) * 40 + rr * 20 + mm] = accg[rr][mm];
        }
        __syncthreads();
        if (tid < 80) {                         // cell: 20 m x 4 j_local
          int mm = tid >> 2, jl = tid & 3;
          int m = half * 20 + mm;
          int j = blk * 4 + jl;
          float gate[4];
#pragma unroll
          for (int g = 0; g < 4; g++) {
            int row16 = jl * 4 + g, w_ = row16 >> 1, rr = row16 & 1;
            float s = 0.f;
#pragma unroll
            for (int grp = 0; grp < 4; grp++) s += part[(w_ * 4 + grp) * 40 + rr * 20 + mm];
            gate[g] = s + b_lstm[g * HH + j];
          }
          float csel;
          if (t == 0) csel = 0.f;
          else {
            const float* cb = s_blank[m] ? c_pre_in : c_new_in;
            csel = cb[(long)s_par[m] * HH + j];
          }
          float cn = sigf(gate[1]) * csel + sigf(gate[0]) * tanhf(gate[2]);
          float hn = sigf(gate[3]) * tanhf(cn);
          long o = (long)m * HH + j;
          h_new_o[o] = hn; c_new_o[o] = cn; c_pre_o[o] = csel;
        }
        __syncthreads();
      }
    }
    gsync();

    // ---- phase J: joint = tanh(tn + h_new @ W_pn + b_joint) ----
    {
      int mh = wav >> 2;
      for (int p = 0; p < 2; ++p) {
        float accj[10];
#pragma unroll
        for (int i = 0; i < 10; i++) accj[i] = 0.f;
#pragma unroll
        for (int q = 0; q < 4; ++q) {
          for (int f = tid; f < 1280; f += NT) {
            int s = f >> 6, l4 = (f & 63) * 4;
            int m = (s >= 10) ? (20 + p * 10 + s - 10) : (p * 10 + s);
            *(float4*)&xs[f * 4] = *(const float4*)&h_new_o[(long)m * HH + q * 256 + l4];
          }
          __syncthreads();
#pragma unroll
          for (int i = 0; i < 10; ++i) {
            float4 x = *(const float4*)&xs[(mh * 10 + i) * 256 + lane * 4];
            FMA4(accj[i], x, wJ[q]);
          }
          __syncthreads();
        }
#pragma unroll
        for (int i = 0; i < 10; i++) accj[i] = rowsum16(accj[i]);
        if ((lane & 15) == 15) {
          int grp = lane >> 4;
#pragma unroll
          for (int i = 0; i < 10; i++) part[(wav * 4 + grp) * 10 + i] = accj[i];
        }
        __syncthreads();
        if (tid < 80) {
          int m_i = tid >> 2, dl2 = tid & 3;
          int mh2 = (m_i >= 10) ? 1 : 0, i = m_i - mh2 * 10;
          int m = mh2 * 20 + p * 10 + i;
          int w2 = mh2 * 4 + dl2;
          float s = 0.f;
#pragma unroll
          for (int grp = 0; grp < 4; grp++) s += part[(w2 * 4 + grp) * 10 + i];
          int d2 = blk * 4 + dl2, b = m / 5;
          float val = s + tn_proj[((long)b * TSTEPS + t) * HH + d2] + b_joint[d2];
          jbuf[(long)m * HH + d2] = tanhf(val);
        }
        __syncthreads();
      }
    }
    gsync();

    // ---- phase L: logits (wL streamed from L2) + local top5 + expsum ----
    {
      int mh = wav >> 2;
      for (int p = 0; p < 2; ++p) {
        float accl[4][10];
#pragma unroll
        for (int r = 0; r < 4; r++)
#pragma unroll
          for (int i = 0; i < 10; i++) accl[r][i] = 0.f;
#pragma unroll
        for (int q = 0; q < 4; ++q) {
          // stream this q-chunk of the 4 owned v-rows (L2-hot on p=1)
          float4 wl[4];
          {
            long vrow = (long)(blk * 16 + (wav & 3) * 4) * HH + q * 256 + lane * 4;
#pragma unroll
            for (int r = 0; r < 4; r++) wl[r] = *(const float4*)&WoutT[vrow + (long)r * HH];
          }
          for (int f = tid; f < 1280; f += NT) {
            int s = f >> 6, l4 = (f & 63) * 4;
            int m = (s >= 10) ? (20 + p * 10 + s - 10) : (p * 10 + s);
            *(float4*)&xs[f * 4] = *(const float4*)&jbuf[(long)m * HH + q * 256 + l4];
          }
          __syncthreads();
#pragma unroll
          for (int i = 0; i < 10; ++i) {
            float4 x = *(const float4*)&xs[(mh * 10 + i) * 256 + lane * 4];
#pragma unroll
            for (int r = 0; r < 4; r++) FMA4(accl[r][i], x, wl[r]);
          }
          __syncthreads();
        }
#pragma unroll
        for (int r = 0; r < 4; r++)
#pragma unroll
          for (int i = 0; i < 10; i++) accl[r][i] = rowsum16(accl[r][i]);
        if ((lane & 15) == 15) {
          int grp = lane >> 4;
#pragma unroll
          for (int r = 0; r < 4; r++)
#pragma unroll
            for (int i = 0; i < 10; i++)
              part[(wav * 4 + grp) * 40 + r * 10 + i] = accl[r][i];
        }
        __syncthreads();
        if (tid < 320) {
          int m_i = tid >> 4, vloc = tid & 15;
          int mh2 = (m_i >= 10) ? 1 : 0, i = m_i - mh2 * 10;
          int m = mh2 * 20 + p * 10 + i;
          int vh2 = vloc >> 2, r = vloc & 3;
          int w2 = mh2 * 4 + vh2;
          float s = 0.f;
#pragma unroll
          for (int grp = 0; grp < 4; grp++) s += part[(w2 * 4 + grp) * 40 + r * 10 + i];
          lg[m * 16 + vloc] = s + b_out[blk * 16 + vloc];
        }
        __syncthreads();
      }
      if (tid < 40) {
        float bv[5]; int bi[5];
#pragma unroll
        for (int j = 0; j < 5; j++) { bv[j] = -3.0e38f; bi[j] = 0x7fffffff; }
        float es = 0.f;
        int cbase = (tid % 5) * 4096 + blk * 16;
#pragma unroll
        for (int vloc = 0; vloc < 16; vloc++) {
          float v = lg[tid * 16 + vloc];
          es += expf(v);
          ins5(bv, bi, v, cbase + vloc);
        }
        int toff = (tid * 256 + blk) * 5;
#pragma unroll
        for (int r = 0; r < 5; r++) { top5v[toff + r] = bv[r]; top5i[toff + r] = bi[r]; }
        expp[tid * 256 + blk] = es;
      }
    }
    gsync();

    // ---- phase B: beam update (blocks 0-7; block = batch) ----
    if (blk < 8) {
      int b = blk;
      int u = t + 1;
      if (wav < 5) {                       // expsum reduce per hyp
        int m = b * 5 + wav;
        float s = expp[m * 256 + lane] + expp[m * 256 + 64 + lane]
                + expp[m * 256 + 128 + lane] + expp[m * 256 + 192 + lane];
#pragma unroll
        for (int off2 = 32; off2 >= 1; off2 >>= 1) s += __shfl_xor(s, off2, 64);
        if (lane == 0) sls[wav] = bscore[wav] - logf(s);
      }
      __syncthreads();
      float bv[5]; int bi[5];
#pragma unroll
      for (int j = 0; j < 5; j++) { bv[j] = -3.0e38f; bi[j] = 0x7fffffff; }
      for (int e = tid; e < 6400; e += NT) {
        int hyp = e / 1280, rem = e - hyp * 1280;
        int blk_i = rem / 5, r = rem - blk_i * 5;
        int idx = ((b * 5 + hyp) * 256 + blk_i) * 5 + r;
        ins5(bv, bi, top5v[idx] + sls[hyp], top5i[idx]);
      }
      __syncthreads();                     // xs free (pv/pi alias)
#pragma unroll
      for (int j = 0; j < 5; j++) { pv[tid * 5 + j] = bv[j]; pi[tid * 5 + j] = bi[j]; }
      __syncthreads();
      if (tid < 64) {
        for (int srcT = tid + 64; srcT < NT; srcT += 64)
#pragma unroll
          for (int j = 0; j < 5; j++) ins5(bv, bi, pv[srcT * 5 + j], pi[srcT * 5 + j]);
        for (int r = 0; r < 5; r++) {
          float mv = bv[0]; int mi = bi[0];
#pragma unroll
          for (int off2 = 32; off2 >= 1; off2 >>= 1) {
            float ov = __shfl_xor(mv, off2, 64);
            int oi = __shfl_xor(mi, off2, 64);
            if (ov > mv || (ov == mv && oi < mi)) { mv = ov; mi = oi; }
          }
          if (bv[0] == mv && bi[0] == mi) {
            bv[0] = bv[1]; bi[0] = bi[1]; bv[1] = bv[2]; bi[1] = bi[2];
            bv[2] = bv[3]; bi[2] = bi[3]; bv[3] = bv[4]; bi[3] = bi[4];
            bv[4] = -3.0e38f; bi[4] = 0x7fffffff;
          }
          if (tid == 0) { outv[r] = mv; outi[r] = mi; }
        }
      }
      __syncthreads();
      if (tid == 0) {
#pragma unroll
        for (int j = 0; j < 5; j++) {
          int idx = outi[j], kp = idx >> 12, tok = idx & 4095;
          int isb = (tok == 0) ? 1 : 0;
          nsc[j] = outv[j];
          nkp[j] = kp;
          nbl[j] = isb;
          ntk[j] = isb ? btok[kp] : tok;
          nol[j] = blen[kp];
          nln[j] = blen[kp] + (isb ? 0 : 1);
        }
#pragma unroll
        for (int j = 0; j < 5; j++) {
          bscore[j] = nsc[j]; btok[j] = ntk[j]; blen[j] = nln[j];
          int gm = b * 5 + j;
          gscores[gm] = nsc[j]; glens[gm] = nln[j];
          gtok[gm] = ntk[j]; gpar[gm] = b * 5 + nkp[j]; gblank[gm] = nbl[j];
        }
      }
      __syncthreads();
      {
        const int* pip = ((u - 1) & 1) ? preds1 : preds0;
        int* pop = (u & 1) ? preds1 : preds0;
        for (int cell = tid; cell < 640; cell += NT) {
          int j = cell >> 7, pos = cell & 127;
          int v = pip[(b * 5 + nkp[j]) * 128 + pos];
          if (!nbl[j] && pos == nol[j]) v = ntk[j];
          pop[(b * 5 + j) * 128 + pos] = v;
        }
      }
    }
    gsync();
  }

  // ---- final output (block 0) ----
  if (blk == 0) {
    if (tid < 40) out[1033 + tid] = gscores[tid] / (float)(glens[tid] + 1);
    if (tid < 8) {
      float bvn = -3.0e38f; int bk = 0;
      for (int k = 0; k < 5; k++) {
        float n = gscores[tid * 5 + k] / (float)(glens[tid * 5 + k] + 1);
        if (n > bvn) { bvn = n; bk = k; }
      }
      s_best[tid] = bk; s_maxn[tid] = bvn;
      out[1024 + tid] = (float)glens[tid * 5 + bk];
    }
    __syncthreads();
    if (tid == 0) {
      float s = 0;
      for (int b = 0; b < 8; b++) s += expf(s_maxn[b]);
      out[1032] = s / 8.f;
    }
    for (int cI = tid; cI < 1024; cI += NT) {
      int b = cI >> 7, pos = cI & 127;
      out[cI] = (float)preds0[(b * 5 + s_best[b]) * 128 + pos];  // u=128 -> preds0
    }
  }
}

// ---------- launch ----------

extern "C" void kernel_launch(void* const* d_in, const int* in_sizes, int n_in,
                              void* d_out, int out_size, void* d_ws, size_t ws_size,
                              hipStream_t stream) {
  const float* tn   = (const float*)d_in[0];
  const float* E    = (const float*)d_in[1];
  const float* Wih  = (const float*)d_in[2];
  const float* Whh  = (const float*)d_in[3];
  const float* bl   = (const float*)d_in[4];
  const float* Wtn  = (const float*)d_in[5];
  const float* Wpn  = (const float*)d_in[6];
  const float* bj   = (const float*)d_in[7];
  const float* Wout = (const float*)d_in[8];
  const float* bo   = (const float*)d_in[9];
  float* out = (float*)d_out;

  unsigned int* bar = (unsigned int*)d_ws;       // 256 B reserved
  float* w = (float*)d_ws + 64;
  size_t off = 0;
  float* tn_proj = w + off; off += 1048576;
  float* WpnT    = w + off; off += 1048576;
  float* WoutT   = w + off; off += 4194304;
  float* jbuf    = w + off; off += 40960;
  float* expp    = w + off; off += 10240;        // [40][256]
  float* top5v   = w + off; off += 51200;        // [40][256][5]
  float* h_pre0  = w + off; off += 40960;
  float* h_pre1  = w + off; off += 40960;
  float* c_pre0  = w + off; off += 40960;
  float* c_pre1  = w + off; off += 40960;
  float* h_new0  = w + off; off += 40960;
  float* h_new1  = w + off; off += 40960;
  float* c_new0  = w + off; off += 40960;
  float* c_new1  = w + off; off += 40960;
  float* gscores = w + off; off += 40;
  int* ib = (int*)(w + off);
  int* top5i  = ib; ib += 51200;
  int* preds0 = ib; ib += 5120;
  int* preds1 = ib; ib += 5120;
  int* glens  = ib; ib += 40;
  int* gtok   = ib; ib += 40;
  int* gpar   = ib; ib += 40;
  int* gblank = ib; ib += 40;
  if (ws_size < (size_t)(64 + off + 61600) * 4) return;   // ~27.2 MB

  (void)hipMemsetAsync(bar, 0, 256, stream);
  k_transp<<<dim3(32, 32), 256, 0, stream>>>(Wpn, WpnT, 1024, 1024);
  k_transp<<<dim3(128, 32), 256, 0, stream>>>(Wout, WoutT, 1024, 4096);
  k_tnproj<<<256, 256, 0, stream>>>(tn, Wtn, tn_proj);

  void* args[] = { (void*)&E, (void*)&Wih, (void*)&Whh, (void*)&bl,
                   (void*)&tn_proj, (void*)&WpnT, (void*)&bj, (void*)&WoutT, (void*)&bo,
                   (void*)&h_pre0, (void*)&h_pre1, (void*)&c_pre0, (void*)&c_pre1,
                   (void*)&h_new0, (void*)&h_new1, (void*)&c_new0, (void*)&c_new1,
                   (void*)&jbuf, (void*)&expp, (void*)&top5v, (void*)&top5i,
                   (void*)&preds0, (void*)&preds1, (void*)&gscores, (void*)&glens,
                   (void*)&gtok, (void*)&gpar, (void*)&gblank,
                   (void*)&bar, (void*)&out };
  (void)hipLaunchCooperativeKernel((void*)k_beam, dim3(NB), dim3(NT), args, 0, stream);
}